// Round 7
// baseline (109.350 us; speedup 1.0000x reference)
//
#include <hip/hip_runtime.h>
#include <math.h>

#define BN_EPS 0.001f
#define CHUNK 4096          // edges per chunk; nchunk = ceil(ne/CHUNK) must be <= 256
#define MAXBUCK 1024        // nbuck = ceil(n/64) must be <= 1024

typedef __attribute__((ext_vector_type(8))) short bf16x8;
typedef __attribute__((ext_vector_type(4))) float f32x4;

__device__ inline unsigned bf16rne(float f) {
  unsigned u = __float_as_uint(f);
  return (u + 0x7fffu + ((u >> 16) & 1u)) >> 16;
}
__device__ inline float bflo(unsigned r) { return __uint_as_float(r << 16); }
__device__ inline float bfhi(unsigned r) { return __uint_as_float(r & 0xffff0000u); }

// ---------------- pass 1: per-chunk LDS histogram by bucket (src>>6) ----------------
__global__ __launch_bounds__(256) void k_ehist(const int2* __restrict__ ep, int ne,
                                               int nbuck, int* __restrict__ ghist) {
  __shared__ int h[MAXBUCK];
  int c = blockIdx.x, t = threadIdx.x;
  for (int i = t; i < nbuck; i += 256) h[i] = 0;
  __syncthreads();
  int base = c * CHUNK;
  int end = min(base + CHUNK, ne);
  for (int e = base + t; e < end; e += 256) atomicAdd(&h[ep[e].x >> 6], 1);
  __syncthreads();
  int* row = ghist + (size_t)c * nbuck;
  for (int i = t; i < nbuck; i += 256) row[i] = h[i];
}

// ---------------- pass 2a: per-bucket exclusive scan over chunks (in place) + totals ----
__global__ __launch_bounds__(256) void k_bscan(int* __restrict__ ghist, int nchunk,
                                               int nbuck, int* __restrict__ btot) {
  __shared__ int s0[256], s1[256];
  int b = blockIdx.x, t = threadIdx.x;
  int v = (t < nchunk) ? ghist[(size_t)t * nbuck + b] : 0;
  s0[t] = v;
  __syncthreads();
  int* src = s0; int* dst = s1;
  for (int off = 1; off < 256; off <<= 1) {
    int x = src[t];
    if (t >= off) x += src[t - off];
    dst[t] = x;
    __syncthreads();
    int* tmp = src; src = dst; dst = tmp;
  }
  if (t < nchunk) ghist[(size_t)t * nbuck + b] = src[t] - v;  // exclusive
  if (t == 0) btot[b] = src[255];                             // total
}

// ---------------- pass 2b: single-block exclusive scan of bucket totals ----------------
__global__ __launch_bounds__(1024) void k_bbase(const int* __restrict__ btot, int nbuck,
                                                int* __restrict__ bbase) {
  __shared__ int s0[1024], s1[1024];
  int t = threadIdx.x;
  int v = (t < nbuck) ? btot[t] : 0;
  s0[t] = v;
  __syncthreads();
  int* src = s0; int* dst = s1;
  for (int off = 1; off < 1024; off <<= 1) {
    int x = src[t];
    if (t >= off) x += src[t - off];
    dst[t] = x;
    __syncthreads();
    int* tmp = src; src = dst; dst = tmp;
  }
  if (t < nbuck) bbase[t] = src[t] - v;
}

// ---------------- pass 3: write packed records to exact slots (LDS cursors) ----------
// record: bits[16:0] = dst, bits[22:17] = src & 63
__global__ __launch_bounds__(256) void k_ebin(const int2* __restrict__ ep, int ne,
                                              int nbuck, const int* __restrict__ ghist,
                                              const int* __restrict__ bbase,
                                              unsigned* __restrict__ bins) {
  __shared__ int cur[MAXBUCK];
  int c = blockIdx.x, t = threadIdx.x;
  const int* row = ghist + (size_t)c * nbuck;
  for (int i = t; i < nbuck; i += 256) cur[i] = bbase[i] + row[i];
  __syncthreads();
  int base = c * CHUNK;
  int end = min(base + CHUNK, ne);
  for (int e = base + t; e < end; e += 256) {
    int2 p = ep[e];
    int pos = atomicAdd(&cur[p.x >> 6], 1);
    bins[pos] = (unsigned)p.y | ((unsigned)(p.x & 63) << 17);
  }
}

// ---------------- per-bucket LDS histogram -> deg ----------------
__global__ __launch_bounds__(256) void k_bcount(const int* __restrict__ bbase,
                                                const int* __restrict__ btot,
                                                const unsigned* __restrict__ bins,
                                                int n, int* __restrict__ deg) {
  __shared__ int h[64];
  int bk = blockIdx.x, t = threadIdx.x;
  if (t < 64) h[t] = 0;
  __syncthreads();
  int s = bbase[bk], cnt = btot[bk];
  for (int i = t; i < cnt; i += 256) atomicAdd(&h[bins[s + i] >> 17], 1);
  __syncthreads();
  if (t < 64) {
    int node = (bk << 6) + t;
    if (node < n) deg[node] = h[t];
  }
}

// ---------------- node-level scan (3 kernels) ----------------
__global__ void k_blocksum(const int* __restrict__ deg, int n, int* __restrict__ bsum) {
  __shared__ int sdata[256];
  int t = threadIdx.x;
  int i = blockIdx.x * 256 + t;
  sdata[t] = (i < n) ? deg[i] : 0;
  __syncthreads();
  for (int s = 128; s > 0; s >>= 1) {
    if (t < s) sdata[t] += sdata[t + s];
    __syncthreads();
  }
  if (t == 0) bsum[blockIdx.x] = sdata[0];
}

__global__ void k_scan_bsums(const int* __restrict__ bsum, int nb, int* __restrict__ boff) {
  __shared__ int s0[256], s1[256];
  int t = threadIdx.x;
  int v = (t < nb) ? bsum[t] : 0;
  s0[t] = v;
  __syncthreads();
  int* src = s0; int* dst = s1;
  for (int off = 1; off < 256; off <<= 1) {
    int x = src[t];
    if (t >= off) x += src[t - off];
    dst[t] = x;
    __syncthreads();
    int* tmp = src; src = dst; dst = tmp;
  }
  if (t < nb) boff[t] = src[t] - v;
}

__global__ void k_scan_final(const int* __restrict__ deg, int n, const int* __restrict__ boff,
                             int* __restrict__ offsets, float* __restrict__ isd) {
  __shared__ int s0[256], s1[256];
  int t = threadIdx.x;
  int i = blockIdx.x * 256 + t;
  int v = (i < n) ? deg[i] : 0;
  s0[t] = v;
  __syncthreads();
  int* src = s0; int* dst = s1;
  for (int off = 1; off < 256; off <<= 1) {
    int x = src[t];
    if (t >= off) x += src[t - off];
    dst[t] = x;
    __syncthreads();
    int* tmp = src; src = dst; dst = tmp;
  }
  if (i < n) {
    offsets[i] = src[t] - v + boff[blockIdx.x];
    isd[i] = 1.0f / sqrtf((float)deg[i]);  // deg==0 -> +inf, matches jnp.power
  }
}

// ---------------- per-bucket CSR fill with LDS cursors ----------------
__global__ __launch_bounds__(256) void k_bfill(const int* __restrict__ bbase,
                                               const int* __restrict__ btot,
                                               const unsigned* __restrict__ bins,
                                               const int* __restrict__ offsets, int n,
                                               int* __restrict__ csr_dst) {
  __shared__ int cur[64];
  int bk = blockIdx.x, t = threadIdx.x;
  if (t < 64) {
    int node = (bk << 6) + t;
    cur[t] = (node < n) ? offsets[node] : 0;
  }
  __syncthreads();
  int s = bbase[bk], cnt = btot[bk];
  for (int i = t; i < cnt; i += 256) {
    unsigned r = bins[s + i];
    int pos = atomicAdd(&cur[r >> 17], 1);
    csr_dst[pos] = (int)(r & 0x1FFFFu);
  }
}

// ---------------- W split+transpose into fragment-major layout (once) ----------------
// For frag = ct*4+ks (ct 0..7, ks 0..3): 64 lanes x 8 shorts contiguous.
// col = ct*16+(lane&15), k = ks*32+(lane>>4)*8+j.
__global__ __launch_bounds__(256) void k_wsplit(const float* __restrict__ W,
                                                unsigned short* __restrict__ Wh,
                                                unsigned short* __restrict__ Wl) {
  int g = blockIdx.x * 256 + threadIdx.x;  // 0..2047
  int frag = g >> 6;                       // 0..31 = ct*4+ks
  int lane = g & 63;
  int ct = frag >> 2, ks = frag & 3;
  int col = ct * 16 + (lane & 15);
  int k0 = ks * 32 + (lane >> 4) * 8;
  unsigned short h8[8], l8[8];
#pragma unroll
  for (int j = 0; j < 8; ++j) {
    float x = W[(size_t)(k0 + j) * 128 + col];
    unsigned short h = (unsigned short)(__float_as_uint(x) >> 16);  // trunc hi
    float rem = x - __uint_as_float((unsigned)h << 16);
    h8[j] = h;
    l8[j] = (unsigned short)bf16rne(rem);
  }
  *(uint4*)&Wh[(size_t)frag * 512 + lane * 8] = *(uint4*)h8;
  *(uint4*)&Wl[(size_t)frag * 512 + lane * 8] = *(uint4*)l8;
}

// ---------------- split-bf16 MFMA GEMM, lean waves: T = X @ W + b ----------------
// Wave = 16 rows x 64 cols. Block = 4 waves = 32 rows (2 row-tiles x 2 col-halves).
// Also writes Tbs = isd[row] * t[row] packed bf16 (gather operand).
__global__ __launch_bounds__(256, 4) void k_gemm(const float* __restrict__ X,
                                                 const unsigned short* __restrict__ Wh,
                                                 const unsigned short* __restrict__ Wl,
                                                 const float* __restrict__ b,
                                                 const float* __restrict__ isd,
                                                 float* __restrict__ T,
                                                 unsigned* __restrict__ Tbs, int M) {
  int tid = threadIdx.x;
  int wave = tid >> 6, lane = tid & 63;
  int r16 = lane & 15, kq = lane >> 4;
  int ch = wave & 1;                              // col half: ct_global = ch*4+ct
  int rowbase = blockIdx.x * 32 + (wave >> 1) * 16;
  int arow = rowbase + r16;
  bool aok = arow < M;
  const float* xr = X + ((size_t)arow << 7);

  // load + split A fragments (16 rows x 128 k per wave)
  bf16x8 ah[4], al[4];
#pragma unroll
  for (int ks = 0; ks < 4; ++ks) {
    int k0 = ks * 32 + kq * 8;
    float4 v0 = aok ? *(const float4*)(xr + k0) : make_float4(0.f, 0.f, 0.f, 0.f);
    float4 v1 = aok ? *(const float4*)(xr + k0 + 4) : make_float4(0.f, 0.f, 0.f, 0.f);
    float f[8] = {v0.x, v0.y, v0.z, v0.w, v1.x, v1.y, v1.z, v1.w};
    bf16x8 h8, l8;
#pragma unroll
    for (int j = 0; j < 8; ++j) {
      unsigned short h = (unsigned short)(__float_as_uint(f[j]) >> 16);
      float rem = f[j] - __uint_as_float((unsigned)h << 16);
      h8[j] = (short)h;
      l8[j] = (short)bf16rne(rem);
    }
    ah[ks] = h8;
    al[ks] = l8;
  }

  f32x4 acc[4] = {};
#pragma unroll
  for (int ks = 0; ks < 4; ++ks) {
#pragma unroll
    for (int ct = 0; ct < 4; ++ct) {
      int frag = (ch * 4 + ct) * 4 + ks;
      bf16x8 bh = *(const bf16x8*)&Wh[(size_t)frag * 512 + lane * 8];
      bf16x8 bl = *(const bf16x8*)&Wl[(size_t)frag * 512 + lane * 8];
      acc[ct] = __builtin_amdgcn_mfma_f32_16x16x32_bf16(ah[ks], bh, acc[ct], 0, 0, 0);
      acc[ct] = __builtin_amdgcn_mfma_f32_16x16x32_bf16(ah[ks], bl, acc[ct], 0, 0, 0);
      acc[ct] = __builtin_amdgcn_mfma_f32_16x16x32_bf16(al[ks], bh, acc[ct], 0, 0, 0);
    }
  }

  // epilogue
  float bias[4];
#pragma unroll
  for (int ct = 0; ct < 4; ++ct) bias[ct] = b[(ch * 4 + ct) * 16 + r16];
  int orow[4];
  float isdr[4];
#pragma unroll
  for (int r = 0; r < 4; ++r) {
    orow[r] = rowbase + kq * 4 + r;
    isdr[r] = (orow[r] < M) ? isd[orow[r]] : 0.f;
  }
#pragma unroll
  for (int ct = 0; ct < 4; ++ct) {
    int col = (ch * 4 + ct) * 16 + r16;
#pragma unroll
    for (int r = 0; r < 4; ++r) {
      float v = acc[ct][r] + bias[ct];
      bool ok = orow[r] < M;
      if (ok) T[((size_t)orow[r] << 7) + col] = v;
      float sv = v * isdr[r];
      float other = __shfl_xor(sv, 1);  // partner column (col^1), same row
      if (ok && !(r16 & 1)) {
        unsigned pk = bf16rne(sv) | (bf16rne(other) << 16);
        Tbs[((size_t)orow[r] << 6) + (ch * 4 + ct) * 8 + (r16 >> 1)] = pk;
      }
    }
  }
}

// ---------------- gather: one wave per node, pre-scaled bf16 neighbor rows ------------
__global__ __launch_bounds__(256) void k_gather(
    const float* __restrict__ T, const unsigned* __restrict__ Tbs,
    const int* __restrict__ deg, const float* __restrict__ isd,
    const int* __restrict__ offsets, const int* __restrict__ csr_dst,
    const float* __restrict__ mm, const float* __restrict__ var,
    const float* __restrict__ gamma, const float* __restrict__ beta,
    float* __restrict__ out, int n) {
  int wave = threadIdx.x >> 6;
  int lane = threadIdx.x & 63;
  int i = blockIdx.x * 4 + wave;
  if (i >= n) return;
  int degi = deg[i];
  int start = offsets[i];
  float sx[8] = {}, sy[8] = {};
  int e = 0;
  for (; e + 8 <= degi; e += 8) {
    int d[8];
#pragma unroll
    for (int j = 0; j < 8; ++j) d[j] = csr_dst[start + e + j];
    unsigned r[8];
#pragma unroll
    for (int j = 0; j < 8; ++j) r[j] = Tbs[((size_t)d[j] << 6) + lane];
#pragma unroll
    for (int j = 0; j < 8; ++j) {
      sx[j] += bflo(r[j]);
      sy[j] += bfhi(r[j]);
    }
  }
  for (; e < degi; ++e) {
    int d = csr_dst[start + e];
    unsigned r = Tbs[((size_t)d << 6) + lane];
    sx[0] += bflo(r);
    sy[0] += bfhi(r);
  }
  float fx = ((sx[0] + sx[1]) + (sx[2] + sx[3])) + ((sx[4] + sx[5]) + (sx[6] + sx[7]));
  float fy = ((sy[0] + sy[1]) + (sy[2] + sy[3])) + ((sy[4] + sy[5]) + (sy[6] + sy[7]));
  float aggx = 0.f, aggy = 0.f;
  if (degi > 0) {
    float2 tv = ((const float2*)(T + ((size_t)i << 7)))[lane];
    float isi = isd[i];
    float di = (float)degi;
    aggx = 0.5f * (isi * fx) + 0.5f * (di * tv.x);
    aggy = 0.5f * (isi * fy) + 0.5f * (di * tv.y);
  }
  float2 mmv = ((const float2*)mm)[lane];
  float2 vv = ((const float2*)var)[lane];
  float2 gv = ((const float2*)gamma)[lane];
  float2 bv = ((const float2*)beta)[lane];
  float2 res;
  res.x = (aggx - mmv.x) * rsqrtf(vv.x + BN_EPS) * gv.x + bv.x;
  res.y = (aggy - mmv.y) * rsqrtf(vv.y + BN_EPS) * gv.y + bv.y;
  ((float2*)(out + ((size_t)i << 7)))[lane] = res;
}

static inline size_t align_up(size_t x) { return (x + 255) & ~(size_t)255; }

extern "C" void kernel_launch(void* const* d_in, const int* in_sizes, int n_in,
                              void* d_out, int out_size, void* d_ws, size_t ws_size,
                              hipStream_t stream) {
  const int2* ep = (const int2*)d_in[0];
  const float* X = (const float*)d_in[1];
  const float* W = (const float*)d_in[2];
  const float* b = (const float*)d_in[3];
  const float* gamma = (const float*)d_in[4];
  const float* beta = (const float*)d_in[5];
  const float* mm = (const float*)d_in[6];
  const float* var = (const float*)d_in[7];
  float* out = (float*)d_out;

  const int ne = in_sizes[0] / 2;
  const int n = in_sizes[1] / 128;
  const int nblk = (n + 255) / 256;      // node-scan blocks, <= 256
  const int nbuck = (n + 63) >> 6;       // <= MAXBUCK
  const int nchunk = (ne + CHUNK - 1) / CHUNK;  // <= 256

  char* p = (char*)d_ws;
  int* deg = (int*)p;        p += align_up((size_t)n * 4);
  float* isd = (float*)p;    p += align_up((size_t)n * 4);
  int* offsets = (int*)p;    p += align_up((size_t)n * 4);
  int* btot = (int*)p;       p += align_up((size_t)nbuck * 4);
  int* bbase = (int*)p;      p += align_up((size_t)nbuck * 4);
  int* bsum = (int*)p;       p += align_up((size_t)nblk * 4);
  int* boff = (int*)p;       p += align_up((size_t)nblk * 4);
  int* ghist = (int*)p;      p += align_up((size_t)nchunk * nbuck * 4);
  int* csr_dst = (int*)p;    p += align_up((size_t)ne * 4);
  unsigned* bins = (unsigned*)p; p += align_up((size_t)ne * 4);
  unsigned short* Wh = (unsigned short*)p; p += align_up((size_t)128 * 128 * 2);
  unsigned short* Wl = (unsigned short*)p; p += align_up((size_t)128 * 128 * 2);
  float* T = (float*)p;      p += align_up((size_t)n * 128 * 4);
  unsigned* Tbs = (unsigned*)p; p += align_up((size_t)n * 64 * 4);

  k_ehist<<<nchunk, 256, 0, stream>>>(ep, ne, nbuck, ghist);
  k_bscan<<<nbuck, 256, 0, stream>>>(ghist, nchunk, nbuck, btot);
  k_bbase<<<1, 1024, 0, stream>>>(btot, nbuck, bbase);
  k_ebin<<<nchunk, 256, 0, stream>>>(ep, ne, nbuck, ghist, bbase, bins);
  k_bcount<<<nbuck, 256, 0, stream>>>(bbase, btot, bins, n, deg);
  k_blocksum<<<nblk, 256, 0, stream>>>(deg, n, bsum);
  k_scan_bsums<<<1, 256, 0, stream>>>(bsum, nblk, boff);
  k_scan_final<<<nblk, 256, 0, stream>>>(deg, n, boff, offsets, isd);
  k_bfill<<<nbuck, 256, 0, stream>>>(bbase, btot, bins, offsets, n, csr_dst);
  k_wsplit<<<8, 256, 0, stream>>>(W, Wh, Wl);
  k_gemm<<<(n + 31) / 32, 256, 0, stream>>>(X, Wh, Wl, b, isd, T, Tbs, n);
  k_gather<<<(n + 3) / 4, 256, 0, stream>>>(T, Tbs, deg, isd, offsets, csr_dst,
                                            mm, var, gamma, beta, out, n);
}

// Round 8
// 100.279 us; speedup vs baseline: 1.0905x; 1.0905x over previous
//
#include <hip/hip_runtime.h>
#include <math.h>

#define BN_EPS 0.001f
#define CHUNK 2048          // edges per chunk; nchunk = ceil(ne/CHUNK) must be <= 512
#define MAXBUCK 1024        // nbuck = ceil(n/64) must be <= 1024

typedef __attribute__((ext_vector_type(8))) short bf16x8;
typedef __attribute__((ext_vector_type(4))) float f32x4;

__device__ inline unsigned bf16rne(float f) {
  unsigned u = __float_as_uint(f);
  return (u + 0x7fffu + ((u >> 16) & 1u)) >> 16;
}
__device__ inline float bflo(unsigned r) { return __uint_as_float(r << 16); }
__device__ inline float bfhi(unsigned r) { return __uint_as_float(r & 0xffff0000u); }

// ---------------- pass 1: per-chunk LDS histogram by bucket (src>>6) ----------------
__global__ __launch_bounds__(256) void k_ehist(const int2* __restrict__ ep, int ne,
                                               int nbuck, int* __restrict__ ghist) {
  __shared__ int h[MAXBUCK];
  int c = blockIdx.x, t = threadIdx.x;
  for (int i = t; i < nbuck; i += 256) h[i] = 0;
  __syncthreads();
  int base = c * CHUNK;
  int end = min(base + CHUNK, ne);
  for (int e = base + t; e < end; e += 256) atomicAdd(&h[ep[e].x >> 6], 1);
  __syncthreads();
  int* row = ghist + (size_t)c * nbuck;
  for (int i = t; i < nbuck; i += 256) row[i] = h[i];
}

// ---------------- pass 2a: per-bucket exclusive scan over chunks (in place) + totals ----
__global__ __launch_bounds__(512) void k_bscan(int* __restrict__ ghist, int nchunk,
                                               int nbuck, int* __restrict__ btot) {
  __shared__ int s0[512], s1[512];
  int b = blockIdx.x, t = threadIdx.x;
  int v = (t < nchunk) ? ghist[(size_t)t * nbuck + b] : 0;
  s0[t] = v;
  __syncthreads();
  int* src = s0; int* dst = s1;
  for (int off = 1; off < 512; off <<= 1) {
    int x = src[t];
    if (t >= off) x += src[t - off];
    dst[t] = x;
    __syncthreads();
    int* tmp = src; src = dst; dst = tmp;
  }
  if (t < nchunk) ghist[(size_t)t * nbuck + b] = src[t] - v;  // exclusive
  if (t == 0) btot[b] = src[511];                             // total
}

// ---------------- pass 2b: single-block exclusive scan of bucket totals ----------------
__global__ __launch_bounds__(1024) void k_bbase(const int* __restrict__ btot, int nbuck,
                                                int* __restrict__ bbase) {
  __shared__ int s0[1024], s1[1024];
  int t = threadIdx.x;
  int v = (t < nbuck) ? btot[t] : 0;
  s0[t] = v;
  __syncthreads();
  int* src = s0; int* dst = s1;
  for (int off = 1; off < 1024; off <<= 1) {
    int x = src[t];
    if (t >= off) x += src[t - off];
    dst[t] = x;
    __syncthreads();
    int* tmp = src; src = dst; dst = tmp;
  }
  if (t < nbuck) bbase[t] = src[t] - v;
}

// ---------------- pass 3: write packed records to exact slots (LDS cursors) ----------
// record: bits[16:0] = dst, bits[22:17] = src & 63
__global__ __launch_bounds__(256) void k_ebin(const int2* __restrict__ ep, int ne,
                                              int nbuck, const int* __restrict__ ghist,
                                              const int* __restrict__ bbase,
                                              unsigned* __restrict__ bins) {
  __shared__ int cur[MAXBUCK];
  int c = blockIdx.x, t = threadIdx.x;
  const int* row = ghist + (size_t)c * nbuck;
  for (int i = t; i < nbuck; i += 256) cur[i] = bbase[i] + row[i];
  __syncthreads();
  int base = c * CHUNK;
  int end = min(base + CHUNK, ne);
  for (int e = base + t; e < end; e += 256) {
    int2 p = ep[e];
    int pos = atomicAdd(&cur[p.x >> 6], 1);
    bins[pos] = (unsigned)p.y | ((unsigned)(p.x & 63) << 17);
  }
}

// ---------------- fused per-bucket: hist -> scan -> deg/isd/offsets -> CSR fill -------
// Bucket base bbase[bk] equals the node-level CSR base for node bk*64 (buckets are in
// node order and cover disjoint node ranges), so no global node scan is needed.
__global__ __launch_bounds__(256) void k_bfinal(const int* __restrict__ bbase,
                                                const int* __restrict__ btot,
                                                const unsigned* __restrict__ bins,
                                                int n, int* __restrict__ deg,
                                                float* __restrict__ isd,
                                                int* __restrict__ offsets,
                                                int* __restrict__ csr_dst) {
  __shared__ int h[64];
  __shared__ int cur[64];
  int bk = blockIdx.x, t = threadIdx.x;
  if (t < 64) h[t] = 0;
  __syncthreads();
  int s = bbase[bk], cnt = btot[bk];
  for (int i = t; i < cnt; i += 256) atomicAdd(&h[bins[s + i] >> 17], 1);
  __syncthreads();
  if (t == 0) {
    int run = s;
    for (int j = 0; j < 64; ++j) { cur[j] = run; run += h[j]; }
  }
  __syncthreads();
  if (t < 64) {
    int node = (bk << 6) + t;
    if (node < n) {
      deg[node] = h[t];
      offsets[node] = cur[t];
      isd[node] = 1.0f / sqrtf((float)h[t]);  // deg==0 -> +inf, matches jnp.power
    }
  }
  __syncthreads();
  for (int i = t; i < cnt; i += 256) {
    unsigned r = bins[s + i];
    int pos = atomicAdd(&cur[r >> 17], 1);
    csr_dst[pos] = (int)(r & 0x1FFFFu);
  }
}

// ---------------- W split+transpose into fragment-major layout (once) ----------------
// For frag = ct*4+ks (ct 0..7, ks 0..3): 64 lanes x 8 shorts contiguous.
// col = ct*16+(lane&15), k = ks*32+(lane>>4)*8+j.
__global__ __launch_bounds__(256) void k_wsplit(const float* __restrict__ W,
                                                unsigned short* __restrict__ Wh,
                                                unsigned short* __restrict__ Wl) {
  int g = blockIdx.x * 256 + threadIdx.x;  // 0..2047
  int frag = g >> 6;                       // 0..31 = ct*4+ks
  int lane = g & 63;
  int ct = frag >> 2, ks = frag & 3;
  int col = ct * 16 + (lane & 15);
  int k0 = ks * 32 + (lane >> 4) * 8;
  unsigned short h8[8], l8[8];
#pragma unroll
  for (int j = 0; j < 8; ++j) {
    float x = W[(size_t)(k0 + j) * 128 + col];
    unsigned short h = (unsigned short)(__float_as_uint(x) >> 16);  // trunc hi
    float rem = x - __uint_as_float((unsigned)h << 16);
    h8[j] = h;
    l8[j] = (unsigned short)bf16rne(rem);
  }
  *(uint4*)&Wh[(size_t)frag * 512 + lane * 8] = *(uint4*)h8;
  *(uint4*)&Wl[(size_t)frag * 512 + lane * 8] = *(uint4*)l8;
}

// ---------------- split-bf16 MFMA GEMM, lean waves: T = X @ W + b ----------------
// Wave = 16 rows x 64 cols. Block = 4 waves = 32 rows (2 row-tiles x 2 col-halves).
// Also writes Tbs = isd[row] * t[row] packed bf16 (gather operand).
__global__ __launch_bounds__(256, 4) void k_gemm(const float* __restrict__ X,
                                                 const unsigned short* __restrict__ Wh,
                                                 const unsigned short* __restrict__ Wl,
                                                 const float* __restrict__ b,
                                                 const float* __restrict__ isd,
                                                 float* __restrict__ T,
                                                 unsigned* __restrict__ Tbs, int M) {
  int tid = threadIdx.x;
  int wave = tid >> 6, lane = tid & 63;
  int r16 = lane & 15, kq = lane >> 4;
  int ch = wave & 1;                              // col half: ct_global = ch*4+ct
  int rowbase = blockIdx.x * 32 + (wave >> 1) * 16;
  int arow = rowbase + r16;
  bool aok = arow < M;
  const float* xr = X + ((size_t)arow << 7);

  // load + split A fragments (16 rows x 128 k per wave)
  bf16x8 ah[4], al[4];
#pragma unroll
  for (int ks = 0; ks < 4; ++ks) {
    int k0 = ks * 32 + kq * 8;
    float4 v0 = aok ? *(const float4*)(xr + k0) : make_float4(0.f, 0.f, 0.f, 0.f);
    float4 v1 = aok ? *(const float4*)(xr + k0 + 4) : make_float4(0.f, 0.f, 0.f, 0.f);
    float f[8] = {v0.x, v0.y, v0.z, v0.w, v1.x, v1.y, v1.z, v1.w};
    bf16x8 h8, l8;
#pragma unroll
    for (int j = 0; j < 8; ++j) {
      unsigned short h = (unsigned short)(__float_as_uint(f[j]) >> 16);
      float rem = f[j] - __uint_as_float((unsigned)h << 16);
      h8[j] = (short)h;
      l8[j] = (short)bf16rne(rem);
    }
    ah[ks] = h8;
    al[ks] = l8;
  }

  f32x4 acc[4] = {};
#pragma unroll
  for (int ks = 0; ks < 4; ++ks) {
#pragma unroll
    for (int ct = 0; ct < 4; ++ct) {
      int frag = (ch * 4 + ct) * 4 + ks;
      bf16x8 bh = *(const bf16x8*)&Wh[(size_t)frag * 512 + lane * 8];
      bf16x8 bl = *(const bf16x8*)&Wl[(size_t)frag * 512 + lane * 8];
      acc[ct] = __builtin_amdgcn_mfma_f32_16x16x32_bf16(ah[ks], bh, acc[ct], 0, 0, 0);
      acc[ct] = __builtin_amdgcn_mfma_f32_16x16x32_bf16(ah[ks], bl, acc[ct], 0, 0, 0);
      acc[ct] = __builtin_amdgcn_mfma_f32_16x16x32_bf16(al[ks], bh, acc[ct], 0, 0, 0);
    }
  }

  // epilogue
  float bias[4];
#pragma unroll
  for (int ct = 0; ct < 4; ++ct) bias[ct] = b[(ch * 4 + ct) * 16 + r16];
  int orow[4];
  float isdr[4];
#pragma unroll
  for (int r = 0; r < 4; ++r) {
    orow[r] = rowbase + kq * 4 + r;
    isdr[r] = (orow[r] < M) ? isd[orow[r]] : 0.f;
  }
#pragma unroll
  for (int ct = 0; ct < 4; ++ct) {
    int col = (ch * 4 + ct) * 16 + r16;
#pragma unroll
    for (int r = 0; r < 4; ++r) {
      float v = acc[ct][r] + bias[ct];
      bool ok = orow[r] < M;
      if (ok) T[((size_t)orow[r] << 7) + col] = v;
      float sv = v * isdr[r];
      float other = __shfl_xor(sv, 1);  // partner column (col^1), same row
      if (ok && !(r16 & 1)) {
        unsigned pk = bf16rne(sv) | (bf16rne(other) << 16);
        Tbs[((size_t)orow[r] << 6) + (ch * 4 + ct) * 8 + (r16 >> 1)] = pk;
      }
    }
  }
}

// ---------------- gather: one wave per node, 16 row-reads in flight ----------------
__global__ __launch_bounds__(256) void k_gather(
    const float* __restrict__ T, const unsigned* __restrict__ Tbs,
    const int* __restrict__ deg, const float* __restrict__ isd,
    const int* __restrict__ offsets, const int* __restrict__ csr_dst,
    const float* __restrict__ mm, const float* __restrict__ var,
    const float* __restrict__ gamma, const float* __restrict__ beta,
    float* __restrict__ out, int n) {
  int wave = threadIdx.x >> 6;
  int lane = threadIdx.x & 63;
  int i = blockIdx.x * 4 + wave;
  if (i >= n) return;
  int degi = deg[i];
  int start = offsets[i];
  float sx[16] = {}, sy[16] = {};
  for (int e = 0; e < degi; e += 16) {
    int d[16];
#pragma unroll
    for (int j = 0; j < 16; ++j)
      d[j] = (e + j < degi) ? csr_dst[start + e + j] : i;  // self row if masked (valid addr)
    unsigned r[16];
#pragma unroll
    for (int j = 0; j < 16; ++j) r[j] = Tbs[((size_t)d[j] << 6) + lane];
#pragma unroll
    for (int j = 0; j < 16; ++j) {
      unsigned rr = (e + j < degi) ? r[j] : 0u;
      sx[j] += bflo(rr);
      sy[j] += bfhi(rr);
    }
  }
  float fx = (((sx[0] + sx[1]) + (sx[2] + sx[3])) + ((sx[4] + sx[5]) + (sx[6] + sx[7]))) +
             (((sx[8] + sx[9]) + (sx[10] + sx[11])) + ((sx[12] + sx[13]) + (sx[14] + sx[15])));
  float fy = (((sy[0] + sy[1]) + (sy[2] + sy[3])) + ((sy[4] + sy[5]) + (sy[6] + sy[7]))) +
             (((sy[8] + sy[9]) + (sy[10] + sy[11])) + ((sy[12] + sy[13]) + (sy[14] + sy[15])));
  float aggx = 0.f, aggy = 0.f;
  if (degi > 0) {
    float2 tv = ((const float2*)(T + ((size_t)i << 7)))[lane];
    float isi = isd[i];
    float di = (float)degi;
    aggx = 0.5f * (isi * fx) + 0.5f * (di * tv.x);
    aggy = 0.5f * (isi * fy) + 0.5f * (di * tv.y);
  }
  float2 mmv = ((const float2*)mm)[lane];
  float2 vv = ((const float2*)var)[lane];
  float2 gv = ((const float2*)gamma)[lane];
  float2 bv = ((const float2*)beta)[lane];
  float2 res;
  res.x = (aggx - mmv.x) * rsqrtf(vv.x + BN_EPS) * gv.x + bv.x;
  res.y = (aggy - mmv.y) * rsqrtf(vv.y + BN_EPS) * gv.y + bv.y;
  ((float2*)(out + ((size_t)i << 7)))[lane] = res;
}

static inline size_t align_up(size_t x) { return (x + 255) & ~(size_t)255; }

extern "C" void kernel_launch(void* const* d_in, const int* in_sizes, int n_in,
                              void* d_out, int out_size, void* d_ws, size_t ws_size,
                              hipStream_t stream) {
  const int2* ep = (const int2*)d_in[0];
  const float* X = (const float*)d_in[1];
  const float* W = (const float*)d_in[2];
  const float* b = (const float*)d_in[3];
  const float* gamma = (const float*)d_in[4];
  const float* beta = (const float*)d_in[5];
  const float* mm = (const float*)d_in[6];
  const float* var = (const float*)d_in[7];
  float* out = (float*)d_out;

  const int ne = in_sizes[0] / 2;
  const int n = in_sizes[1] / 128;
  const int nbuck = (n + 63) >> 6;              // <= MAXBUCK
  const int nchunk = (ne + CHUNK - 1) / CHUNK;  // <= 512

  char* p = (char*)d_ws;
  int* deg = (int*)p;        p += align_up((size_t)n * 4);
  float* isd = (float*)p;    p += align_up((size_t)n * 4);
  int* offsets = (int*)p;    p += align_up((size_t)n * 4);
  int* btot = (int*)p;       p += align_up((size_t)nbuck * 4);
  int* bbase = (int*)p;      p += align_up((size_t)nbuck * 4);
  int* ghist = (int*)p;      p += align_up((size_t)nchunk * nbuck * 4);
  int* csr_dst = (int*)p;    p += align_up((size_t)ne * 4);
  unsigned* bins = (unsigned*)p; p += align_up((size_t)ne * 4);
  unsigned short* Wh = (unsigned short*)p; p += align_up((size_t)128 * 128 * 2);
  unsigned short* Wl = (unsigned short*)p; p += align_up((size_t)128 * 128 * 2);
  float* T = (float*)p;      p += align_up((size_t)n * 128 * 4);
  unsigned* Tbs = (unsigned*)p; p += align_up((size_t)n * 64 * 4);

  k_ehist<<<nchunk, 256, 0, stream>>>(ep, ne, nbuck, ghist);
  k_bscan<<<nbuck, 512, 0, stream>>>(ghist, nchunk, nbuck, btot);
  k_bbase<<<1, 1024, 0, stream>>>(btot, nbuck, bbase);
  k_ebin<<<nchunk, 256, 0, stream>>>(ep, ne, nbuck, ghist, bbase, bins);
  k_bfinal<<<nbuck, 256, 0, stream>>>(bbase, btot, bins, n, deg, isd, offsets, csr_dst);
  k_wsplit<<<8, 256, 0, stream>>>(W, Wh, Wl);
  k_gemm<<<(n + 31) / 32, 256, 0, stream>>>(X, Wh, Wl, b, isd, T, Tbs, n);
  k_gather<<<(n + 3) / 4, 256, 0, stream>>>(T, Tbs, deg, isd, offsets, csr_dst,
                                            mm, var, gamma, beta, out, n);
}

// Round 9
// 96.129 us; speedup vs baseline: 1.1375x; 1.0432x over previous
//
#include <hip/hip_runtime.h>
#include <math.h>

#define BN_EPS 0.001f
#define CHUNK 2048          // edges per chunk; nchunk = ceil(ne/CHUNK) must be <= 512
#define MAXBUCK 1024        // nbuck = ceil(n/64) must be <= 1024

typedef __attribute__((ext_vector_type(8))) short bf16x8;
typedef __attribute__((ext_vector_type(4))) float f32x4;
typedef __attribute__((ext_vector_type(2))) float f32x2;

__device__ inline unsigned bf16rne(float f) {
  unsigned u = __float_as_uint(f);
  return (u + 0x7fffu + ((u >> 16) & 1u)) >> 16;
}

// ---------------- pass 1: per-chunk LDS histogram by bucket (src>>6) ----------------
__global__ __launch_bounds__(256) void k_ehist(const int2* __restrict__ ep, int ne,
                                               int nbuck, int* __restrict__ ghist) {
  __shared__ int h[MAXBUCK];
  int c = blockIdx.x, t = threadIdx.x;
  for (int i = t; i < nbuck; i += 256) h[i] = 0;
  __syncthreads();
  int base = c * CHUNK;
  int end = min(base + CHUNK, ne);
  for (int e = base + t; e < end; e += 256) atomicAdd(&h[ep[e].x >> 6], 1);
  __syncthreads();
  int* row = ghist + (size_t)c * nbuck;
  for (int i = t; i < nbuck; i += 256) row[i] = h[i];
}

// ---------------- pass 2a: per-bucket exclusive scan over chunks (in place) + totals ----
__global__ __launch_bounds__(512) void k_bscan(int* __restrict__ ghist, int nchunk,
                                               int nbuck, int* __restrict__ btot) {
  __shared__ int s0[512], s1[512];
  int b = blockIdx.x, t = threadIdx.x;
  int v = (t < nchunk) ? ghist[(size_t)t * nbuck + b] : 0;
  s0[t] = v;
  __syncthreads();
  int* src = s0; int* dst = s1;
  for (int off = 1; off < 512; off <<= 1) {
    int x = src[t];
    if (t >= off) x += src[t - off];
    dst[t] = x;
    __syncthreads();
    int* tmp = src; src = dst; dst = tmp;
  }
  if (t < nchunk) ghist[(size_t)t * nbuck + b] = src[t] - v;  // exclusive
  if (t == 0) btot[b] = src[511];                             // total
}

// ---------------- pass 2b: single-block exclusive scan of bucket totals ----------------
__global__ __launch_bounds__(1024) void k_bbase(const int* __restrict__ btot, int nbuck,
                                                int* __restrict__ bbase) {
  __shared__ int s0[1024], s1[1024];
  int t = threadIdx.x;
  int v = (t < nbuck) ? btot[t] : 0;
  s0[t] = v;
  __syncthreads();
  int* src = s0; int* dst = s1;
  for (int off = 1; off < 1024; off <<= 1) {
    int x = src[t];
    if (t >= off) x += src[t - off];
    dst[t] = x;
    __syncthreads();
    int* tmp = src; src = dst; dst = tmp;
  }
  if (t < nbuck) bbase[t] = src[t] - v;
}

// ---------------- pass 3: write packed records to exact slots (LDS cursors) ----------
// record: bits[16:0] = dst, bits[22:17] = src & 63
__global__ __launch_bounds__(256) void k_ebin(const int2* __restrict__ ep, int ne,
                                              int nbuck, const int* __restrict__ ghist,
                                              const int* __restrict__ bbase,
                                              unsigned* __restrict__ bins) {
  __shared__ int cur[MAXBUCK];
  int c = blockIdx.x, t = threadIdx.x;
  const int* row = ghist + (size_t)c * nbuck;
  for (int i = t; i < nbuck; i += 256) cur[i] = bbase[i] + row[i];
  __syncthreads();
  int base = c * CHUNK;
  int end = min(base + CHUNK, ne);
  for (int e = base + t; e < end; e += 256) {
    int2 p = ep[e];
    int pos = atomicAdd(&cur[p.x >> 6], 1);
    bins[pos] = (unsigned)p.y | ((unsigned)(p.x & 63) << 17);
  }
}

// ---------------- fused per-bucket: hist -> scan -> deg/isd/offsets -> CSR fill -------
__global__ __launch_bounds__(256) void k_bfinal(const int* __restrict__ bbase,
                                                const int* __restrict__ btot,
                                                const unsigned* __restrict__ bins,
                                                int n, int* __restrict__ deg,
                                                float* __restrict__ isd,
                                                int* __restrict__ offsets,
                                                int* __restrict__ csr_dst) {
  __shared__ int h[64];
  __shared__ int cur[64];
  int bk = blockIdx.x, t = threadIdx.x;
  if (t < 64) h[t] = 0;
  __syncthreads();
  int s = bbase[bk], cnt = btot[bk];
  for (int i = t; i < cnt; i += 256) atomicAdd(&h[bins[s + i] >> 17], 1);
  __syncthreads();
  if (t == 0) {
    int run = s;
    for (int j = 0; j < 64; ++j) { cur[j] = run; run += h[j]; }
  }
  __syncthreads();
  if (t < 64) {
    int node = (bk << 6) + t;
    if (node < n) {
      deg[node] = h[t];
      offsets[node] = cur[t];
      isd[node] = 1.0f / sqrtf((float)h[t]);  // deg==0 -> +inf, matches jnp.power
    }
  }
  __syncthreads();
  for (int i = t; i < cnt; i += 256) {
    unsigned r = bins[s + i];
    int pos = atomicAdd(&cur[r >> 17], 1);
    csr_dst[pos] = (int)(r & 0x1FFFFu);
  }
}

// ---------------- W split+transpose into fragment-major layout (once) ----------------
__global__ __launch_bounds__(256) void k_wsplit(const float* __restrict__ W,
                                                unsigned short* __restrict__ Wh,
                                                unsigned short* __restrict__ Wl) {
  int g = blockIdx.x * 256 + threadIdx.x;  // 0..2047
  int frag = g >> 6;                       // 0..31 = ct*4+ks
  int lane = g & 63;
  int ct = frag >> 2, ks = frag & 3;
  int col = ct * 16 + (lane & 15);
  int k0 = ks * 32 + (lane >> 4) * 8;
  unsigned short h8[8], l8[8];
#pragma unroll
  for (int j = 0; j < 8; ++j) {
    float x = W[(size_t)(k0 + j) * 128 + col];
    unsigned short h = (unsigned short)(__float_as_uint(x) >> 16);  // trunc hi
    float rem = x - __uint_as_float((unsigned)h << 16);
    h8[j] = h;
    l8[j] = (unsigned short)bf16rne(rem);
  }
  *(uint4*)&Wh[(size_t)frag * 512 + lane * 8] = *(uint4*)h8;
  *(uint4*)&Wl[(size_t)frag * 512 + lane * 8] = *(uint4*)l8;
}

// ---------------- split-bf16 MFMA GEMM, lean waves: T = X @ W + b ----------------
// Wave = 16 rows x 64 cols. Block = 4 waves = 32 rows (2 row-tiles x 2 col-halves).
// Writes fp32 T and fp8-e4m3 Tb8 = fp8(isd[row] * t[row]) (gather operand, 128B/row).
__global__ __launch_bounds__(256, 4) void k_gemm(const float* __restrict__ X,
                                                 const unsigned short* __restrict__ Wh,
                                                 const unsigned short* __restrict__ Wl,
                                                 const float* __restrict__ b,
                                                 const float* __restrict__ isd,
                                                 float* __restrict__ T,
                                                 unsigned char* __restrict__ Tb8, int M) {
  int tid = threadIdx.x;
  int wave = tid >> 6, lane = tid & 63;
  int r16 = lane & 15, kq = lane >> 4;
  int ch = wave & 1;                              // col half: ct_global = ch*4+ct
  int rowbase = blockIdx.x * 32 + (wave >> 1) * 16;
  int arow = rowbase + r16;
  bool aok = arow < M;
  const float* xr = X + ((size_t)arow << 7);

  // load + split A fragments (16 rows x 128 k per wave)
  bf16x8 ah[4], al[4];
#pragma unroll
  for (int ks = 0; ks < 4; ++ks) {
    int k0 = ks * 32 + kq * 8;
    float4 v0 = aok ? *(const float4*)(xr + k0) : make_float4(0.f, 0.f, 0.f, 0.f);
    float4 v1 = aok ? *(const float4*)(xr + k0 + 4) : make_float4(0.f, 0.f, 0.f, 0.f);
    float f[8] = {v0.x, v0.y, v0.z, v0.w, v1.x, v1.y, v1.z, v1.w};
    bf16x8 h8, l8;
#pragma unroll
    for (int j = 0; j < 8; ++j) {
      unsigned short h = (unsigned short)(__float_as_uint(f[j]) >> 16);
      float rem = f[j] - __uint_as_float((unsigned)h << 16);
      h8[j] = (short)h;
      l8[j] = (short)bf16rne(rem);
    }
    ah[ks] = h8;
    al[ks] = l8;
  }

  f32x4 acc[4] = {};
#pragma unroll
  for (int ks = 0; ks < 4; ++ks) {
#pragma unroll
    for (int ct = 0; ct < 4; ++ct) {
      int frag = (ch * 4 + ct) * 4 + ks;
      bf16x8 bh = *(const bf16x8*)&Wh[(size_t)frag * 512 + lane * 8];
      bf16x8 bl = *(const bf16x8*)&Wl[(size_t)frag * 512 + lane * 8];
      acc[ct] = __builtin_amdgcn_mfma_f32_16x16x32_bf16(ah[ks], bh, acc[ct], 0, 0, 0);
      acc[ct] = __builtin_amdgcn_mfma_f32_16x16x32_bf16(ah[ks], bl, acc[ct], 0, 0, 0);
      acc[ct] = __builtin_amdgcn_mfma_f32_16x16x32_bf16(al[ks], bh, acc[ct], 0, 0, 0);
    }
  }

  // epilogue
  float bias[4];
#pragma unroll
  for (int ct = 0; ct < 4; ++ct) bias[ct] = b[(ch * 4 + ct) * 16 + r16];
  int orow[4];
  float isdr[4];
#pragma unroll
  for (int r = 0; r < 4; ++r) {
    orow[r] = rowbase + kq * 4 + r;
    isdr[r] = (orow[r] < M) ? isd[orow[r]] : 0.f;
  }
#pragma unroll
  for (int ct = 0; ct < 4; ++ct) {
    int col = (ch * 4 + ct) * 16 + r16;
#pragma unroll
    for (int r = 0; r < 4; ++r) {
      float v = acc[ct][r] + bias[ct];
      bool ok = orow[r] < M;
      if (ok) T[((size_t)orow[r] << 7) + col] = v;
      float sv = v * isdr[r];
      float other = __shfl_xor(sv, 1);  // col^1, same row
      // pack 4 cols into one dword of fp8: even lanes pack (c,c+1), then pull (c+2,c+3)
      int pk01 = __builtin_amdgcn_cvt_pk_fp8_f32(sv, other, 0, false);
      int pk23 = __shfl_xor(pk01, 2);
      if (ok && (r16 & 3) == 0) {
        unsigned dword = ((unsigned)pk01 & 0xFFFFu) | ((unsigned)pk23 << 16);
        *(unsigned*)&Tb8[((size_t)orow[r] << 7) + (ch * 4 + ct) * 16 + r16] = dword;
      }
    }
  }
}

// ---------------- gather: one wave per node, fp8 rows (128B), 16 reads in flight ------
__global__ __launch_bounds__(256) void k_gather(
    const float* __restrict__ T, const unsigned char* __restrict__ Tb8,
    const int* __restrict__ deg, const float* __restrict__ isd,
    const int* __restrict__ offsets, const int* __restrict__ csr_dst,
    const float* __restrict__ mm, const float* __restrict__ var,
    const float* __restrict__ gamma, const float* __restrict__ beta,
    float* __restrict__ out, int n, int ne) {
  int wave = threadIdx.x >> 6;
  int lane = threadIdx.x & 63;
  int i = blockIdx.x * 4 + wave;
  if (i >= n) return;
  int degi = deg[i];
  int start = offsets[i];
  const unsigned short* rows = (const unsigned short*)Tb8;  // row stride 64 ushorts
  float sx[16] = {}, sy[16] = {};
  for (int e = 0; e < degi; e += 16) {
    int ii = start + e + (lane & 15);
    int dv = (ii < ne) ? csr_dst[ii] : 0;  // coalesced index load (64B line)
    unsigned short r[16];
#pragma unroll
    for (int j = 0; j < 16; ++j) {
      int idx = __shfl(dv, j);
      r[j] = rows[((size_t)idx << 6) + lane];  // 2 fp8 cols per lane
    }
#pragma unroll
    for (int j = 0; j < 16; ++j) {
      int rr = (e + j < degi) ? (int)r[j] : 0;
      f32x2 f = __builtin_amdgcn_cvt_pk_f32_fp8(rr, false);
      sx[j] += f.x;
      sy[j] += f.y;
    }
  }
  float fx = (((sx[0] + sx[1]) + (sx[2] + sx[3])) + ((sx[4] + sx[5]) + (sx[6] + sx[7]))) +
             (((sx[8] + sx[9]) + (sx[10] + sx[11])) + ((sx[12] + sx[13]) + (sx[14] + sx[15])));
  float fy = (((sy[0] + sy[1]) + (sy[2] + sy[3])) + ((sy[4] + sy[5]) + (sy[6] + sy[7]))) +
             (((sy[8] + sy[9]) + (sy[10] + sy[11])) + ((sy[12] + sy[13]) + (sy[14] + sy[15])));
  float aggx = 0.f, aggy = 0.f;
  if (degi > 0) {
    float2 tv = ((const float2*)(T + ((size_t)i << 7)))[lane];
    float isi = isd[i];
    float di = (float)degi;
    aggx = 0.5f * (isi * fx) + 0.5f * (di * tv.x);
    aggy = 0.5f * (isi * fy) + 0.5f * (di * tv.y);
  }
  float2 mmv = ((const float2*)mm)[lane];
  float2 vv = ((const float2*)var)[lane];
  float2 gv = ((const float2*)gamma)[lane];
  float2 bv = ((const float2*)beta)[lane];
  float2 res;
  res.x = (aggx - mmv.x) * rsqrtf(vv.x + BN_EPS) * gv.x + bv.x;
  res.y = (aggy - mmv.y) * rsqrtf(vv.y + BN_EPS) * gv.y + bv.y;
  ((float2*)(out + ((size_t)i << 7)))[lane] = res;
}

static inline size_t align_up(size_t x) { return (x + 255) & ~(size_t)255; }

extern "C" void kernel_launch(void* const* d_in, const int* in_sizes, int n_in,
                              void* d_out, int out_size, void* d_ws, size_t ws_size,
                              hipStream_t stream) {
  const int2* ep = (const int2*)d_in[0];
  const float* X = (const float*)d_in[1];
  const float* W = (const float*)d_in[2];
  const float* b = (const float*)d_in[3];
  const float* gamma = (const float*)d_in[4];
  const float* beta = (const float*)d_in[5];
  const float* mm = (const float*)d_in[6];
  const float* var = (const float*)d_in[7];
  float* out = (float*)d_out;

  const int ne = in_sizes[0] / 2;
  const int n = in_sizes[1] / 128;
  const int nbuck = (n + 63) >> 6;              // <= MAXBUCK
  const int nchunk = (ne + CHUNK - 1) / CHUNK;  // <= 512

  char* p = (char*)d_ws;
  int* deg = (int*)p;        p += align_up((size_t)n * 4);
  float* isd = (float*)p;    p += align_up((size_t)n * 4);
  int* offsets = (int*)p;    p += align_up((size_t)n * 4);
  int* btot = (int*)p;       p += align_up((size_t)nbuck * 4);
  int* bbase = (int*)p;      p += align_up((size_t)nbuck * 4);
  int* ghist = (int*)p;      p += align_up((size_t)nchunk * nbuck * 4);
  int* csr_dst = (int*)p;    p += align_up((size_t)ne * 4);
  unsigned* bins = (unsigned*)p; p += align_up((size_t)ne * 4);
  unsigned short* Wh = (unsigned short*)p; p += align_up((size_t)128 * 128 * 2);
  unsigned short* Wl = (unsigned short*)p; p += align_up((size_t)128 * 128 * 2);
  float* T = (float*)p;      p += align_up((size_t)n * 128 * 4);
  unsigned char* Tb8 = (unsigned char*)p; p += align_up((size_t)n * 128);

  k_ehist<<<nchunk, 256, 0, stream>>>(ep, ne, nbuck, ghist);
  k_bscan<<<nbuck, 512, 0, stream>>>(ghist, nchunk, nbuck, btot);
  k_bbase<<<1, 1024, 0, stream>>>(btot, nbuck, bbase);
  k_ebin<<<nchunk, 256, 0, stream>>>(ep, ne, nbuck, ghist, bbase, bins);
  k_bfinal<<<nbuck, 256, 0, stream>>>(bbase, btot, bins, n, deg, isd, offsets, csr_dst);
  k_wsplit<<<8, 256, 0, stream>>>(W, Wh, Wl);
  k_gemm<<<(n + 31) / 32, 256, 0, stream>>>(X, Wh, Wl, b, isd, T, Tb8, n);
  k_gather<<<(n + 3) / 4, 256, 0, stream>>>(T, Tb8, deg, isd, offsets, csr_dst,
                                            mm, var, gamma, beta, out, n, ne);
}